// Round 4
// baseline (6496.646 us; speedup 1.0000x reference)
//
#include <hip/hip_runtime.h>
#include <hip/hip_cooperative_groups.h>
#include <math.h>

namespace cg = cooperative_groups;

#define T_LEN   16384
#define NB      2
#define FCH     80
#define NLAYERS 24
#define TFRAMES 68
#define TILE    32

typedef __attribute__((ext_vector_type(8))) short bf16x8;
typedef __attribute__((ext_vector_type(4))) float f32x4;

static __device__ inline unsigned short f2bf(float f) {
    unsigned int u = __float_as_uint(f);
    unsigned int r = (u + 0x7FFFu + ((u >> 16) & 1u)) >> 16;
    return (unsigned short)r;
}

// ---------------------------------------------------------------------------
// Pack: bf16 weight layouts + firstWT (transposed embedding table, bias folded)
// ---------------------------------------------------------------------------
__global__ void k_pack(const float* __restrict__ convW, const float* __restrict__ condW,
                       const float* __restrict__ skipW, const float* __restrict__ resW,
                       const float* __restrict__ last1W, const float* __restrict__ last2W,
                       const float* __restrict__ firstW, const float* __restrict__ firstb,
                       unsigned short* __restrict__ ATb, unsigned short* __restrict__ SRTb,
                       unsigned short* __restrict__ W1b, unsigned short* __restrict__ W2b,
                       float* __restrict__ firstWT) {
    int idx = blockIdx.x * 256 + threadIdx.x;
    const int nAT = NLAYERS * 128 * 288;
    const int nSR = NLAYERS * 128 * 64;
    if (idx < nAT) {
        int k = idx % 288;
        int o = (idx / 288) & 127;
        int l = idx / (288 * 128);
        float v = 0.f;
        if (k < 192) v = convW[(((l * 128 + o) * 64) + (k & 63)) * 3 + (k >> 6)];
        else if (k - 192 < 80) v = condW[(l * 128 + o) * 80 + (k - 192)];
        ATb[idx] = f2bf(v);
    } else if (idx < nAT + nSR) {
        int j = idx - nAT;
        int k = j & 63;
        int o2 = (j >> 6) & 127;
        int l = j / (64 * 128);
        float v = (o2 < 64) ? skipW[(l * 64 + o2) * 64 + k]
                            : resW[(l * 64 + (o2 - 64)) * 64 + k];
        SRTb[j] = f2bf(v);
    } else if (idx < nAT + nSR + 4096) {
        W1b[idx - nAT - nSR] = f2bf(last1W[idx - nAT - nSR]);
    } else if (idx < nAT + nSR + 4096 + 16384) {
        int j = idx - nAT - nSR - 4096;
        W2b[j] = f2bf(last2W[j]);
    } else if (idx < nAT + nSR + 4096 + 16384 + 16384) {
        int j = idx - nAT - nSR - 4096 - 16384;
        int xs = j >> 6, c = j & 63;
        firstWT[j] = firstW[c * 256 + xs] + firstb[c];
    }
}

// ---------------------------------------------------------------------------
// Embedding -> bf16 time-major buffer (megakernel path)
// ---------------------------------------------------------------------------
__global__ void k_embed_h(const int* __restrict__ x, const float* __restrict__ firstWT,
                          unsigned short* __restrict__ outH) {
    int idx = blockIdx.x * 256 + threadIdx.x;
    if (idx >= NB * T_LEN * 64) return;
    int c = idx & 63;
    int t = (idx >> 6) & (T_LEN - 1);
    int b = idx >> 20;
    int xs = (t == 0) ? 0 : x[b * T_LEN + t - 1];
    outH[idx] = f2bf(firstWT[xs * 64 + c]);
}

// ---------------------------------------------------------------------------
// Embedding -> fp32 master + zero skip (fallback path)
// ---------------------------------------------------------------------------
__global__ void k_embed_f(const int* __restrict__ x, const float* __restrict__ firstWT,
                          float* __restrict__ outF, float* __restrict__ skip) {
    int idx = blockIdx.x * 256 + threadIdx.x;
    if (idx >= NB * T_LEN * 64) return;
    int c = idx & 63;
    int t = (idx >> 6) & (T_LEN - 1);
    int b = idx >> 20;
    int xs = (t == 0) ? 0 : x[b * T_LEN + t - 1];
    outF[idx] = firstWT[xs * 64 + c];
    skip[idx] = 0.f;
}

// ---------------------------------------------------------------------------
// ConvIn: valid conv, kernel 5, (B,80,68) -> (B,80,64)   (c-major, fp32)
// ---------------------------------------------------------------------------
__global__ void k_convin(const float* __restrict__ feat, const float* __restrict__ W,
                         float* __restrict__ f0) {
    int idx = blockIdx.x * 256 + threadIdx.x;
    if (idx >= NB * FCH * 64) return;
    int t = idx & 63;
    int o = (idx >> 6) % FCH;
    int b = idx / (64 * FCH);
    const float* fb = feat + b * FCH * TFRAMES;
    const float* wo = W + o * FCH * 5;
    float acc = 0.f;
    for (int i = 0; i < FCH; ++i) {
        const float* fi = fb + i * TFRAMES + t;
        const float* wi = wo + i * 5;
#pragma unroll
        for (int k = 0; k < 5; ++k) acc += fi[k] * wi[k];
    }
    f0[idx] = acc;
}

// ---------------------------------------------------------------------------
// Upsample stage (x4 repeat + 9-tap smooth), fp32 c-major
// ---------------------------------------------------------------------------
__global__ void k_up(const float* __restrict__ in, float* __restrict__ out,
                     const float* __restrict__ kern, int Tin) {
    int Tout = Tin * 4;
    int idx = blockIdx.x * 256 + threadIdx.x;
    if (idx >= NB * FCH * Tout) return;
    int t = idx % Tout;
    int bc = idx / Tout;
    const float* ib = in + bc * Tin;
    float acc = 0.f;
#pragma unroll
    for (int k = 0; k < 9; ++k) {
        int u = t + k - 4;
        if (u >= 0 && u < Tout) acc += kern[k] * ib[u >> 2];
    }
    out[idx] = acc;
}

// ---------------------------------------------------------------------------
// Last upsample -> bf16 TIME-MAJOR [b][t][96], LDS-staged source frames
// ---------------------------------------------------------------------------
__global__ __launch_bounds__(256)
void k_up_last(const float* __restrict__ in, unsigned short* __restrict__ outH,
               const float* __restrict__ kern) {
    __shared__ float sF[18 * 80];
    const int tid = threadIdx.x;
    const int b  = blockIdx.x >> 8;
    const int t0 = (blockIdx.x & 255) * 64;
    const int fr0 = (t0 >> 2) - 1;

    for (int idx = tid; idx < 18 * 80; idx += 256) {
        int c = idx / 18, fr = idx - c * 18;
        int gfr = fr0 + fr;
        float v = 0.f;
        if (gfr >= 0 && gfr < 4096) v = in[((size_t)b * 80 + c) * 4096 + gfr];
        sF[fr * 80 + c] = v;
    }
    float kr[9];
#pragma unroll
    for (int k = 0; k < 9; ++k) kr[k] = kern[k];
    __syncthreads();

    for (int idx = tid; idx < 64 * 96; idx += 256) {
        int c = idx % 96;
        int t = idx / 96;
        float acc = 0.f;
        if (c < 80) {
            int ubase = t0 + t - 4;
#pragma unroll
            for (int k = 0; k < 9; ++k) {
                int fr = ((ubase + k) >> 2) - fr0;
                acc += kr[k] * sF[fr * 80 + c];
            }
        }
        outH[((size_t)b * T_LEN + t0 + t) * 96 + c] = f2bf(acc);
    }
}

// ---------------------------------------------------------------------------
// MEGAKERNEL: all 24 layers + last1/last2 tail. Cooperative launch, 1024 blocks.
// Per-block: 32 time cols, all 128 gate channels. Skip + own-tile residual in
// registers across layers; bf16 residual mirror in global for halo exchange.
// ---------------------------------------------------------------------------
__global__ __launch_bounds__(256, 4)
void k_mega(const int* __restrict__ x, const float* __restrict__ firstWT,
            unsigned short* __restrict__ bufA, unsigned short* __restrict__ bufB,
            const unsigned short* __restrict__ ffb,
            const unsigned short* __restrict__ ATb, const unsigned short* __restrict__ SRTb,
            const float* __restrict__ convB, const float* __restrict__ skipB,
            const float* __restrict__ resB,
            const unsigned short* __restrict__ W1b, const unsigned short* __restrict__ W2b,
            const float* __restrict__ b1, const float* __restrict__ b2,
            float* __restrict__ outp)
{
    __shared__ __align__(16) unsigned short s_X[96 * 72];    // residual tile+halo [u][c]
    __shared__ __align__(16) unsigned short s_F[32 * 104];   // cond features [t][kf]
    __shared__ __align__(16) unsigned short s_Z[32 * 72];    // z / skip staging [t][c]

    cg::grid_group gg = cg::this_grid();

    const int tid  = threadIdx.x;
    const int b    = blockIdx.x >> 9;
    const int t0   = (blockIdx.x & 511) * TILE;
    const int lane = tid & 63;
    const int wv   = tid >> 6;
    const int col  = lane & 15;
    const int quad = lane >> 4;
    const int ch   = 16 * wv + 4 * quad;    // C/D row base for this lane

    // stage cond features ONCE (reused by all 24 layers)
    {
        const unsigned short* fp = ffb + ((size_t)b * T_LEN + t0) * 96;
        for (int idx = tid; idx < 32 * 12; idx += 256) {
            int t = idx / 12, seg = idx - t * 12;
            *(bf16x8*)(&s_F[t * 104 + seg * 8]) = *(const bf16x8*)(fp + t * 96 + seg * 8);
        }
    }

    // init: own-tile residual fp32 (exact, stays in regs), skip accumulator
    f32x4 resReg[2], skipAcc[2];
#pragma unroll
    for (int nt = 0; nt < 2; ++nt) {
        int t = t0 + nt * 16 + col;
        int xs = (t == 0) ? 0 : x[b * T_LEN + t - 1];
        resReg[nt] = *(const f32x4*)(firstWT + xs * 64 + ch);
        skipAcc[nt] = (f32x4){0.f, 0.f, 0.f, 0.f};
    }
    unsigned short* bufs[2] = {bufA, bufB};

    for (int l = 0; l < NLAYERS; ++l) {
        const int d = 1 << (l % 6);
        const int W = TILE + 2 * d;
        const unsigned short* bin = bufs[l & 1] + (size_t)b * T_LEN * 64;

        // stage residual tile + causal halo (bf16 copy)
        for (int idx = tid; idx < W * 8; idx += 256) {
            int u = idx >> 3, seg = idx & 7;
            int g = t0 - 2 * d + u;
            bf16x8 v = {0, 0, 0, 0, 0, 0, 0, 0};
            if (g >= 0) v = *(const bf16x8*)(bin + (size_t)g * 64 + seg * 8);
            *(bf16x8*)(&s_X[u * 72 + seg * 8]) = v;
        }
        __syncthreads();

        // ---- GEMM1: h(128 x 32t) = AT^T * [X-taps ; F], K=288, A streamed ----
        const unsigned short* AL = ATb + (size_t)l * 128 * 288;
        const size_t ro0 = (size_t)(16 * wv + col) * 288 + quad * 8;
        const size_t ro1 = ro0 + (size_t)64 * 288;
        f32x4 acc0[2], acc1[2];
        acc0[0] = acc0[1] = acc1[0] = acc1[1] = (f32x4){0.f, 0.f, 0.f, 0.f};
        bf16x8 a0 = *(const bf16x8*)(AL + ro0);
        bf16x8 a1 = *(const bf16x8*)(AL + ro1);
#pragma unroll
        for (int ks = 0; ks < 9; ++ks) {
            bf16x8 n0 = a0, n1 = a1;
            if (ks < 8) {
                n0 = *(const bf16x8*)(AL + ro0 + (ks + 1) * 32);
                n1 = *(const bf16x8*)(AL + ro1 + (ks + 1) * 32);
            }
#pragma unroll
            for (int nt = 0; nt < 2; ++nt) {
                bf16x8 fB;
                if (ks < 6) {
                    int k = ks * 32 + quad * 8;
                    int u = nt * 16 + col + (k >> 6) * d;
                    fB = *(const bf16x8*)(&s_X[u * 72 + (k & 63)]);
                } else {
                    fB = *(const bf16x8*)(&s_F[(nt * 16 + col) * 104 + (ks - 6) * 32 + quad * 8]);
                }
                acc0[nt] = __builtin_amdgcn_mfma_f32_16x16x32_bf16(a0, fB, acc0[nt], 0, 0, 0);
                acc1[nt] = __builtin_amdgcn_mfma_f32_16x16x32_bf16(a1, fB, acc1[nt], 0, 0, 0);
            }
            a0 = n0; a1 = n1;
        }

        // ---- bias + gated activation -> s_Z bf16 ----
        f32x4 cbA = *(const f32x4*)(convB + l * 128 + ch);
        f32x4 cbG = *(const f32x4*)(convB + l * 128 + 64 + ch);
#pragma unroll
        for (int nt = 0; nt < 2; ++nt) {
            unsigned int pk[2];
#pragma unroll
            for (int r2 = 0; r2 < 2; ++r2) {
                float zz[2];
#pragma unroll
                for (int e = 0; e < 2; ++e) {
                    float av = acc0[nt][2 * r2 + e] + cbA[2 * r2 + e];
                    float gv = acc1[nt][2 * r2 + e] + cbG[2 * r2 + e];
                    float th = 1.f - 2.f * __builtin_amdgcn_rcpf(__expf(2.f * av) + 1.f);
                    float sg = __builtin_amdgcn_rcpf(1.f + __expf(-gv));
                    zz[e] = th * sg;
                }
                pk[r2] = (unsigned int)f2bf(zz[0]) | ((unsigned int)f2bf(zz[1]) << 16);
            }
            unsigned int* zp = (unsigned int*)(&s_Z[(nt * 16 + col) * 72 + ch]);
            zp[0] = pk[0];
            zp[1] = pk[1];
        }
        __syncthreads();

        // ---- GEMM2: [skip;res](128 x 32t) = SRT^T * Z, K=64 ----
        const unsigned short* SL = SRTb + (size_t)l * 128 * 64;
        bf16x8 w00 = *(const bf16x8*)(SL + (size_t)(16 * wv + col) * 64 + quad * 8);
        bf16x8 w01 = *(const bf16x8*)(SL + (size_t)(16 * wv + col) * 64 + 32 + quad * 8);
        bf16x8 w10 = *(const bf16x8*)(SL + (size_t)(16 * wv + 64 + col) * 64 + quad * 8);
        bf16x8 w11 = *(const bf16x8*)(SL + (size_t)(16 * wv + 64 + col) * 64 + 32 + quad * 8);
        f32x4 acs[2], acr[2];
        acs[0] = acs[1] = acr[0] = acr[1] = (f32x4){0.f, 0.f, 0.f, 0.f};
#pragma unroll
        for (int nt = 0; nt < 2; ++nt) {
            bf16x8 fz0 = *(const bf16x8*)(&s_Z[(nt * 16 + col) * 72 + quad * 8]);
            bf16x8 fz1 = *(const bf16x8*)(&s_Z[(nt * 16 + col) * 72 + 32 + quad * 8]);
            acs[nt] = __builtin_amdgcn_mfma_f32_16x16x32_bf16(w00, fz0, acs[nt], 0, 0, 0);
            acs[nt] = __builtin_amdgcn_mfma_f32_16x16x32_bf16(w01, fz1, acs[nt], 0, 0, 0);
            acr[nt] = __builtin_amdgcn_mfma_f32_16x16x32_bf16(w10, fz0, acr[nt], 0, 0, 0);
            acr[nt] = __builtin_amdgcn_mfma_f32_16x16x32_bf16(w11, fz1, acr[nt], 0, 0, 0);
        }

        // ---- epilogue: in-register skip/residual accumulation ----
        f32x4 sb4 = *(const f32x4*)(skipB + l * 64 + ch);
        f32x4 rb4 = *(const f32x4*)(resB + l * 64 + ch);
        if (l != NLAYERS - 1) {
            unsigned short* bout = bufs[(l + 1) & 1] + (size_t)b * T_LEN * 64;
#pragma unroll
            for (int nt = 0; nt < 2; ++nt) {
#pragma unroll
                for (int e = 0; e < 4; ++e) {
                    skipAcc[nt][e] += acs[nt][e] + sb4[e];
                    resReg[nt][e]  += acr[nt][e] + rb4[e];
                }
                unsigned int p01 = (unsigned int)f2bf(resReg[nt][0]) |
                                   ((unsigned int)f2bf(resReg[nt][1]) << 16);
                unsigned int p23 = (unsigned int)f2bf(resReg[nt][2]) |
                                   ((unsigned int)f2bf(resReg[nt][3]) << 16);
                unsigned int* hp = (unsigned int*)(bout + ((size_t)(t0 + nt * 16 + col)) * 64 + ch);
                hp[0] = p01;
                hp[1] = p23;
            }
            __threadfence();
            gg.sync();
            __threadfence();
        } else {
#pragma unroll
            for (int nt = 0; nt < 2; ++nt)
#pragma unroll
                for (int e = 0; e < 4; ++e)
                    skipAcc[nt][e] += acs[nt][e] + sb4[e];
        }
    }

    // ---------------- tail: relu(skip) -> last1 -> relu -> last2 ----------------
    __syncthreads();   // all waves done reading s_Z
#pragma unroll
    for (int nt = 0; nt < 2; ++nt) {
        float v0 = fmaxf(skipAcc[nt][0], 0.f), v1 = fmaxf(skipAcc[nt][1], 0.f);
        float v2 = fmaxf(skipAcc[nt][2], 0.f), v3 = fmaxf(skipAcc[nt][3], 0.f);
        unsigned int* zp = (unsigned int*)(&s_Z[(nt * 16 + col) * 72 + ch]);
        zp[0] = (unsigned int)f2bf(v0) | ((unsigned int)f2bf(v1) << 16);
        zp[1] = (unsigned int)f2bf(v2) | ((unsigned int)f2bf(v3) << 16);
    }
    __syncthreads();

    // last1: h2 = relu(W1 @ relu(skip) + b1)
    f32x4 aL[2];
    aL[0] = aL[1] = (f32x4){0.f, 0.f, 0.f, 0.f};
#pragma unroll
    for (int ks = 0; ks < 2; ++ks) {
        bf16x8 fw = *(const bf16x8*)(W1b + (size_t)(16 * wv + col) * 64 + ks * 32 + quad * 8);
#pragma unroll
        for (int nt = 0; nt < 2; ++nt) {
            bf16x8 fz = *(const bf16x8*)(&s_Z[(nt * 16 + col) * 72 + ks * 32 + quad * 8]);
            aL[nt] = __builtin_amdgcn_mfma_f32_16x16x32_bf16(fw, fz, aL[nt], 0, 0, 0);
        }
    }
    f32x4 bb1 = *(const f32x4*)(b1 + ch);
#pragma unroll
    for (int nt = 0; nt < 2; ++nt) {
        float h0 = fmaxf(aL[nt][0] + bb1[0], 0.f), h1 = fmaxf(aL[nt][1] + bb1[1], 0.f);
        float h2 = fmaxf(aL[nt][2] + bb1[2], 0.f), h3 = fmaxf(aL[nt][3] + bb1[3], 0.f);
        unsigned int* hp = (unsigned int*)(&s_X[(nt * 16 + col) * 72 + ch]);
        hp[0] = (unsigned int)f2bf(h0) | ((unsigned int)f2bf(h1) << 16);
        hp[1] = (unsigned int)f2bf(h2) | ((unsigned int)f2bf(h3) << 16);
    }
    __syncthreads();

    // last2: out = W2 @ h2 + b2  (256 out channels, fp32 c-major)
    f32x4 aO[4][2];
#pragma unroll
    for (int p = 0; p < 4; ++p) aO[p][0] = aO[p][1] = (f32x4){0.f, 0.f, 0.f, 0.f};
#pragma unroll
    for (int ks = 0; ks < 2; ++ks) {
        bf16x8 fz0 = *(const bf16x8*)(&s_X[(0 * 16 + col) * 72 + ks * 32 + quad * 8]);
        bf16x8 fz1 = *(const bf16x8*)(&s_X[(1 * 16 + col) * 72 + ks * 32 + quad * 8]);
#pragma unroll
        for (int p = 0; p < 4; ++p) {
            bf16x8 fw = *(const bf16x8*)(W2b + (size_t)(16 * (wv + 4 * p) + col) * 64
                                         + ks * 32 + quad * 8);
            aO[p][0] = __builtin_amdgcn_mfma_f32_16x16x32_bf16(fw, fz0, aO[p][0], 0, 0, 0);
            aO[p][1] = __builtin_amdgcn_mfma_f32_16x16x32_bf16(fw, fz1, aO[p][1], 0, 0, 0);
        }
    }
#pragma unroll
    for (int p = 0; p < 4; ++p) {
        int o0 = 16 * (wv + 4 * p) + 4 * quad;
        f32x4 bb2 = *(const f32x4*)(b2 + o0);
#pragma unroll
        for (int nt = 0; nt < 2; ++nt) {
            int t = t0 + nt * 16 + col;
#pragma unroll
            for (int e = 0; e < 4; ++e)
                outp[((size_t)b * 256 + o0 + e) * T_LEN + t] = aO[p][nt][e] + bb2[e];
        }
    }
}

// ---------------------------------------------------------------------------
// FALLBACK path (round-3 layer kernel + tail), used only if cooperative
// launch is unavailable.
// ---------------------------------------------------------------------------
__global__ __launch_bounds__(256, 4)
void k_layer(const float* __restrict__ prevF, float* __restrict__ nextF,
             float* __restrict__ skip, const unsigned short* __restrict__ ffb,
             const unsigned short* __restrict__ ATb, const unsigned short* __restrict__ SRTb,
             const float* __restrict__ convB, const float* __restrict__ skipB,
             const float* __restrict__ resB, int d)
{
    __shared__ __align__(16) unsigned short s_X[96 * 72];
    __shared__ __align__(16) unsigned short s_Z[32 * 72];
    const int tid = threadIdx.x;
    const int b   = blockIdx.x >> 9;
    const int t0  = (blockIdx.x & 511) * TILE;
    const int W   = TILE + 2 * d;
    {
        const float* xb = prevF + ((size_t)b * T_LEN) * 64;
        for (int idx = tid; idx < W * 8; idx += 256) {
            int u = idx >> 3, seg = idx & 7;
            int g = t0 - 2 * d + u;
            bf16x8 v = {0, 0, 0, 0, 0, 0, 0, 0};
            if (g >= 0) {
                const float* p = xb + (size_t)g * 64 + seg * 8;
                f32x4 x0 = *(const f32x4*)p;
                f32x4 x1 = *(const f32x4*)(p + 4);
                v[0] = (short)f2bf(x0[0]); v[1] = (short)f2bf(x0[1]);
                v[2] = (short)f2bf(x0[2]); v[3] = (short)f2bf(x0[3]);
                v[4] = (short)f2bf(x1[0]); v[5] = (short)f2bf(x1[1]);
                v[6] = (short)f2bf(x1[2]); v[7] = (short)f2bf(x1[3]);
            }
            *(bf16x8*)(&s_X[u * 72 + seg * 8]) = v;
        }
    }
    const int lane = tid & 63, wv = tid >> 6, col = lane & 15, quad = lane >> 4;
    bf16x8 frA[2][9];
#pragma unroll
    for (int p = 0; p < 2; ++p)
#pragma unroll
        for (int ks = 0; ks < 9; ++ks)
            frA[p][ks] = *(const bf16x8*)(ATb + (size_t)(16 * wv + 64 * p + col) * 288
                                          + ks * 32 + quad * 8);
    f32x4 acc[2][2];
#pragma unroll
    for (int p = 0; p < 2; ++p)
#pragma unroll
        for (int nt = 0; nt < 2; ++nt) acc[p][nt] = (f32x4){0.f, 0.f, 0.f, 0.f};
    const unsigned short* fp = ffb + ((size_t)b * T_LEN + t0) * 96;
    __syncthreads();
#pragma unroll
    for (int ks = 0; ks < 9; ++ks) {
#pragma unroll
        for (int nt = 0; nt < 2; ++nt) {
            bf16x8 fB;
            if (ks < 6) {
                int k = ks * 32 + quad * 8;
                int u = nt * 16 + col + (k >> 6) * d;
                fB = *(const bf16x8*)(&s_X[u * 72 + (k & 63)]);
            } else {
                fB = *(const bf16x8*)(fp + (nt * 16 + col) * 96 + (ks - 6) * 32 + quad * 8);
            }
            acc[0][nt] = __builtin_amdgcn_mfma_f32_16x16x32_bf16(frA[0][ks], fB, acc[0][nt], 0, 0, 0);
            acc[1][nt] = __builtin_amdgcn_mfma_f32_16x16x32_bf16(frA[1][ks], fB, acc[1][nt], 0, 0, 0);
        }
    }
    f32x4 cbA = *(const f32x4*)(convB + 16 * wv + quad * 4);
    f32x4 cbG = *(const f32x4*)(convB + 64 + 16 * wv + quad * 4);
#pragma unroll
    for (int nt = 0; nt < 2; ++nt) {
        unsigned int pk[2];
#pragma unroll
        for (int r2 = 0; r2 < 2; ++r2) {
            float zz[2];
#pragma unroll
            for (int e = 0; e < 2; ++e) {
                float a = acc[0][nt][2 * r2 + e] + cbA[2 * r2 + e];
                float g = acc[1][nt][2 * r2 + e] + cbG[2 * r2 + e];
                float th = 1.f - 2.f * __builtin_amdgcn_rcpf(__expf(2.f * a) + 1.f);
                float sg = __builtin_amdgcn_rcpf(1.f + __expf(-g));
                zz[e] = th * sg;
            }
            pk[r2] = (unsigned int)f2bf(zz[0]) | ((unsigned int)f2bf(zz[1]) << 16);
        }
        unsigned int* zp = (unsigned int*)(&s_Z[(nt * 16 + col) * 72 + 16 * wv + quad * 4]);
        zp[0] = pk[0];
        zp[1] = pk[1];
    }
    bf16x8 frA2[2][2];
#pragma unroll
    for (int p = 0; p < 2; ++p)
#pragma unroll
        for (int ks = 0; ks < 2; ++ks)
            frA2[p][ks] = *(const bf16x8*)(SRTb + (size_t)(16 * wv + 64 * p + col) * 64
                                           + ks * 32 + quad * 8);
    __syncthreads();
    f32x4 acc2[2][2];
#pragma unroll
    for (int p = 0; p < 2; ++p)
#pragma unroll
        for (int nt = 0; nt < 2; ++nt) acc2[p][nt] = (f32x4){0.f, 0.f, 0.f, 0.f};
#pragma unroll
    for (int ks = 0; ks < 2; ++ks)
#pragma unroll
        for (int nt = 0; nt < 2; ++nt) {
            bf16x8 fz = *(const bf16x8*)(&s_Z[(nt * 16 + col) * 72 + ks * 32 + quad * 8]);
            acc2[0][nt] = __builtin_amdgcn_mfma_f32_16x16x32_bf16(frA2[0][ks], fz, acc2[0][nt], 0, 0, 0);
            acc2[1][nt] = __builtin_amdgcn_mfma_f32_16x16x32_bf16(frA2[1][ks], fz, acc2[1][nt], 0, 0, 0);
        }
    f32x4 sb4 = *(const f32x4*)(skipB + 16 * wv + quad * 4);
    f32x4 rb4 = *(const f32x4*)(resB + 16 * wv + quad * 4);
#pragma unroll
    for (int nt = 0; nt < 2; ++nt) {
        size_t base = (((size_t)b * T_LEN) + t0 + nt * 16 + col) * 64 + 16 * wv + quad * 4;
        f32x4 s = *(f32x4*)(skip + base);
        f32x4 r = *(const f32x4*)(prevF + base);
#pragma unroll
        for (int e = 0; e < 4; ++e) {
            s[e] += acc2[0][nt][e] + sb4[e];
            r[e] += acc2[1][nt][e] + rb4[e];
        }
        *(f32x4*)(skip + base) = s;
        *(f32x4*)(nextF + base) = r;
    }
}

__global__ __launch_bounds__(256)
void k_last1(const float* __restrict__ skip, const unsigned short* __restrict__ W1b,
             const float* __restrict__ b1, unsigned short* __restrict__ h2b) {
    __shared__ __align__(16) unsigned short s_S[64 * 72];
    const int tid = threadIdx.x;
    const int b = blockIdx.x >> 8;
    const int t0 = (blockIdx.x & 255) * 64;
    const float* sp = skip + (((size_t)b * T_LEN) + t0) * 64;
    for (int idx = tid; idx < 64 * 32; idx += 256) {
        int t = idx >> 5, c2 = idx & 31;
        float v0 = fmaxf(sp[t * 64 + 2 * c2], 0.f);
        float v1 = fmaxf(sp[t * 64 + 2 * c2 + 1], 0.f);
        *(unsigned int*)(&s_S[t * 72 + 2 * c2]) =
            (unsigned int)f2bf(v0) | ((unsigned int)f2bf(v1) << 16);
    }
    const int lane = tid & 63, wv = tid >> 6, col = lane & 15, quad = lane >> 4;
    bf16x8 fa[2];
#pragma unroll
    for (int ks = 0; ks < 2; ++ks)
        fa[ks] = *(const bf16x8*)(W1b + (16 * wv + col) * 64 + ks * 32 + quad * 8);
    f32x4 acc[4];
#pragma unroll
    for (int nt = 0; nt < 4; ++nt) acc[nt] = (f32x4){0.f, 0.f, 0.f, 0.f};
    __syncthreads();
#pragma unroll
    for (int ks = 0; ks < 2; ++ks)
#pragma unroll
        for (int nt = 0; nt < 4; ++nt) {
            bf16x8 fz = *(const bf16x8*)(&s_S[(nt * 16 + col) * 72 + ks * 32 + quad * 8]);
            acc[nt] = __builtin_amdgcn_mfma_f32_16x16x32_bf16(fa[ks], fz, acc[nt], 0, 0, 0);
        }
    f32x4 bb = *(const f32x4*)(b1 + 16 * wv + quad * 4);
#pragma unroll
    for (int nt = 0; nt < 4; ++nt) {
        float h0 = fmaxf(acc[nt][0] + bb[0], 0.f), h1 = fmaxf(acc[nt][1] + bb[1], 0.f);
        float h2 = fmaxf(acc[nt][2] + bb[2], 0.f), h3 = fmaxf(acc[nt][3] + bb[3], 0.f);
        unsigned short* hp = h2b + (((size_t)b * T_LEN) + t0 + nt * 16 + col) * 64
                             + 16 * wv + quad * 4;
        ((unsigned int*)hp)[0] = (unsigned int)f2bf(h0) | ((unsigned int)f2bf(h1) << 16);
        ((unsigned int*)hp)[1] = (unsigned int)f2bf(h2) | ((unsigned int)f2bf(h3) << 16);
    }
}

__global__ __launch_bounds__(256)
void k_last2(const unsigned short* __restrict__ h2b, const unsigned short* __restrict__ W2b,
             const float* __restrict__ b2, float* __restrict__ out) {
    __shared__ __align__(16) unsigned short s_H[64 * 72];
    const int tid = threadIdx.x;
    const int b = blockIdx.x >> 8;
    const int t0 = (blockIdx.x & 255) * 64;
    const unsigned short* hp = h2b + (((size_t)b * T_LEN) + t0) * 64;
    for (int idx = tid; idx < 64 * 8; idx += 256) {
        int t = idx >> 3, seg = idx & 7;
        *(bf16x8*)(&s_H[t * 72 + seg * 8]) = *(const bf16x8*)(hp + t * 64 + seg * 8);
    }
    const int lane = tid & 63, wv = tid >> 6, col = lane & 15, quad = lane >> 4;
    bf16x8 fa[4][2];
#pragma unroll
    for (int p = 0; p < 4; ++p)
#pragma unroll
        for (int ks = 0; ks < 2; ++ks)
            fa[p][ks] = *(const bf16x8*)(W2b + (size_t)(16 * (wv + 4 * p) + col) * 64
                                         + ks * 32 + quad * 8);
    f32x4 acc[4][4];
#pragma unroll
    for (int p = 0; p < 4; ++p)
#pragma unroll
        for (int nt = 0; nt < 4; ++nt) acc[p][nt] = (f32x4){0.f, 0.f, 0.f, 0.f};
    __syncthreads();
#pragma unroll
    for (int ks = 0; ks < 2; ++ks)
#pragma unroll
        for (int nt = 0; nt < 4; ++nt) {
            bf16x8 fz = *(const bf16x8*)(&s_H[(nt * 16 + col) * 72 + ks * 32 + quad * 8]);
#pragma unroll
            for (int p = 0; p < 4; ++p)
                acc[p][nt] = __builtin_amdgcn_mfma_f32_16x16x32_bf16(fa[p][ks], fz, acc[p][nt], 0, 0, 0);
        }
#pragma unroll
    for (int p = 0; p < 4; ++p) {
        f32x4 bb = *(const f32x4*)(b2 + 16 * (wv + 4 * p) + quad * 4);
#pragma unroll
        for (int nt = 0; nt < 4; ++nt) {
            int t = t0 + nt * 16 + col;
#pragma unroll
            for (int e = 0; e < 4; ++e) {
                int o = 16 * (wv + 4 * p) + quad * 4 + e;
                out[((size_t)b * 256 + o) * T_LEN + t] = acc[p][nt][e] + bb[e];
            }
        }
    }
}

// ---------------------------------------------------------------------------
extern "C" void kernel_launch(void* const* d_in, const int* in_sizes, int n_in,
                              void* d_out, int out_size, void* d_ws, size_t ws_size,
                              hipStream_t stream) {
    const int*   x       = (const int*)  d_in[0];
    const float* feature = (const float*)d_in[1];
    const float* firstW  = (const float*)d_in[2];
    const float* firstb  = (const float*)d_in[3];
    const float* convW   = (const float*)d_in[4];
    const float* convB   = (const float*)d_in[5];
    const float* condW   = (const float*)d_in[6];
    const float* skipW   = (const float*)d_in[7];
    const float* skipB   = (const float*)d_in[8];
    const float* resW    = (const float*)d_in[9];
    const float* resB    = (const float*)d_in[10];
    const float* last1W  = (const float*)d_in[11];
    const float* last1b  = (const float*)d_in[12];
    const float* last2W  = (const float*)d_in[13];
    const float* last2b  = (const float*)d_in[14];
    const float* convinW = (const float*)d_in[15];
    const float* upK     = (const float*)d_in[16];

    // layout: small fp32 scratch, then a big region unioned between
    // mega path (bufA/bufB bf16) and fallback path (outAF/outBF/skip/h2b)
    float* ws = (float*)d_ws;
    float* f0      = ws;                      // 10240
    float* f1      = f0 + 10240;              // 40960
    float* f2      = f1 + 40960;              // 163840
    float* f3      = f2 + 163840;             // 655360
    float* firstWT = f3 + 655360;             // 16384
    float* big     = firstWT + 16384;         // union region: 7*2^20 floats (28 MB)
    // mega view
    unsigned short* bufA = (unsigned short*)big;                 // 2097152 ush
    unsigned short* bufB = bufA + 2097152;                       // 2097152 ush
    // fallback view
    float* outAF = big;                                          // 2097152 f
    float* outBF = outAF + 2097152;                              // 2097152 f
    float* skip  = outBF + 2097152;                              // 2097152 f
    unsigned short* h2b = (unsigned short*)(skip + 2097152);     // 2097152 ush
    // common tail region
    float* endf = big + 7 * 1048576;
    unsigned short* ffb  = (unsigned short*)endf;                // 3145728 ush
    unsigned short* ATb  = ffb + 3145728;                        // 884736
    unsigned short* SRTb = ATb + 884736;                         // 196608
    unsigned short* W1b  = SRTb + 196608;                        // 4096
    unsigned short* W2b  = W1b + 4096;                           // 16384

    int n;
    n = NLAYERS * 128 * 288 + NLAYERS * 128 * 64 + 4096 + 16384 + 16384;
    k_pack<<<(n + 255) / 256, 256, 0, stream>>>(convW, condW, skipW, resW, last1W, last2W,
                                                firstW, firstb, ATb, SRTb, W1b, W2b, firstWT);
    n = NB * FCH * 64;
    k_convin<<<(n + 255) / 256, 256, 0, stream>>>(feature, convinW, f0);
    k_up<<<(NB * FCH * 256 + 255) / 256, 256, 0, stream>>>(f0, f1, upK + 0, 64);
    k_up<<<(NB * FCH * 1024 + 255) / 256, 256, 0, stream>>>(f1, f2, upK + 9, 256);
    k_up<<<(NB * FCH * 4096 + 255) / 256, 256, 0, stream>>>(f2, f3, upK + 18, 1024);
    k_up_last<<<NB * 256, 256, 0, stream>>>(f3, ffb, upK + 27);

    int coop = 0;
    int dev = 0;
    hipGetDevice(&dev);
    hipDeviceGetAttribute(&coop, hipDeviceAttributeCooperativeLaunch, dev);

    bool done = false;
    if (coop) {
        n = NB * T_LEN * 64;
        k_embed_h<<<(n + 255) / 256, 256, 0, stream>>>(x, firstWT, bufA);
        float* outp = (float*)d_out;
        void* args[] = {(void*)&x, (void*)&firstWT, (void*)&bufA, (void*)&bufB,
                        (void*)&ffb, (void*)&ATb, (void*)&SRTb,
                        (void*)&convB, (void*)&skipB, (void*)&resB,
                        (void*)&W1b, (void*)&W2b, (void*)&last1b, (void*)&last2b,
                        (void*)&outp};
        hipError_t err = hipLaunchCooperativeKernel((const void*)k_mega, dim3(NB * 512),
                                                    dim3(256), args, 0, stream);
        done = (err == hipSuccess);
    }
    if (!done) {
        n = NB * T_LEN * 64;
        k_embed_f<<<(n + 255) / 256, 256, 0, stream>>>(x, firstWT, outAF, skip);
        float* poF = outAF;
        float* pnF = outBF;
        for (int l = 0; l < NLAYERS; ++l) {
            int d = 1 << (l % 6);
            k_layer<<<NB * (T_LEN / TILE), 256, 0, stream>>>(
                poF, pnF, skip, ffb,
                ATb + (size_t)l * 128 * 288, SRTb + (size_t)l * 128 * 64,
                convB + l * 128, skipB + l * 64, resB + l * 64, d);
            float* tf = poF; poF = pnF; pnF = tf;
        }
        k_last1<<<NB * 256, 256, 0, stream>>>(skip, W1b, last1b, h2b);
        k_last2<<<NB * 256, 256, 0, stream>>>(h2b, W2b, last2b, (float*)d_out);
    }
}

// Round 5
// 469.255 us; speedup vs baseline: 13.8446x; 13.8446x over previous
//
#include <hip/hip_runtime.h>
#include <math.h>

#define T_LEN   16384
#define NB      2
#define FCH     80
#define NLAYERS 24
#define TFRAMES 68
#define TILE    32

typedef __attribute__((ext_vector_type(8))) short bf16x8;
typedef __attribute__((ext_vector_type(4))) float f32x4;

static __device__ inline unsigned short f2bf(float f) {
    unsigned int u = __float_as_uint(f);
    unsigned int r = (u + 0x7FFFu + ((u >> 16) & 1u)) >> 16;
    return (unsigned short)r;
}

// ---------------------------------------------------------------------------
// Pack: bf16 weight layouts, firstWT (bias folded), ASKb (skipW^T, K=l*64+c),
// sbSum (summed skip biases)
// ---------------------------------------------------------------------------
__global__ void k_pack(const float* __restrict__ convW, const float* __restrict__ condW,
                       const float* __restrict__ skipW, const float* __restrict__ resW,
                       const float* __restrict__ last1W, const float* __restrict__ last2W,
                       const float* __restrict__ firstW, const float* __restrict__ firstb,
                       const float* __restrict__ skipB,
                       unsigned short* __restrict__ ATb, unsigned short* __restrict__ SRTb,
                       unsigned short* __restrict__ W1b, unsigned short* __restrict__ W2b,
                       float* __restrict__ firstWT, unsigned short* __restrict__ ASKb,
                       float* __restrict__ sbSum) {
    int idx = blockIdx.x * 256 + threadIdx.x;
    const int nAT = NLAYERS * 128 * 288;
    const int nSR = NLAYERS * 128 * 64;
    const int e0 = nAT, e1 = e0 + nSR, e2 = e1 + 4096, e3 = e2 + 16384,
              e4 = e3 + 16384, e5 = e4 + 64 * 1536, e6 = e5 + 64;
    if (idx < e0) {
        int k = idx % 288;
        int o = (idx / 288) & 127;
        int l = idx / (288 * 128);
        float v = 0.f;
        if (k < 192) v = convW[(((l * 128 + o) * 64) + (k & 63)) * 3 + (k >> 6)];
        else if (k - 192 < 80) v = condW[(l * 128 + o) * 80 + (k - 192)];
        ATb[idx] = f2bf(v);
    } else if (idx < e1) {
        int j = idx - e0;
        int k = j & 63;
        int o2 = (j >> 6) & 127;
        int l = j / (64 * 128);
        float v = (o2 < 64) ? skipW[(l * 64 + o2) * 64 + k]
                            : resW[(l * 64 + (o2 - 64)) * 64 + k];
        SRTb[j] = f2bf(v);
    } else if (idx < e2) {
        W1b[idx - e1] = f2bf(last1W[idx - e1]);
    } else if (idx < e3) {
        W2b[idx - e2] = f2bf(last2W[idx - e2]);
    } else if (idx < e4) {
        int j = idx - e3;
        int xs = j >> 6, c = j & 63;
        firstWT[j] = firstW[c * 256 + xs] + firstb[c];
    } else if (idx < e5) {
        int j = idx - e4;
        int o = j / 1536, k = j % 1536;
        int l = k >> 6, c = k & 63;
        ASKb[j] = f2bf(skipW[(l * 64 + o) * 64 + c]);
    } else if (idx < e6) {
        int o = idx - e5;
        float s = 0.f;
        for (int l = 0; l < NLAYERS; ++l) s += skipB[l * 64 + o];
        sbSum[o] = s;
    }
}

// ---------------------------------------------------------------------------
// Embedding -> fp32 time-major (fast path: no skip buffer)
// ---------------------------------------------------------------------------
__global__ void k_embed2(const int* __restrict__ x, const float* __restrict__ firstWT,
                         float* __restrict__ outF) {
    int idx = blockIdx.x * 256 + threadIdx.x;
    if (idx >= NB * T_LEN * 64) return;
    int c = idx & 63;
    int t = (idx >> 6) & (T_LEN - 1);
    int b = idx >> 20;
    int xs = (t == 0) ? 0 : x[b * T_LEN + t - 1];
    outF[idx] = firstWT[xs * 64 + c];
}

// fallback variant: also zero skip
__global__ void k_embed_f(const int* __restrict__ x, const float* __restrict__ firstWT,
                          float* __restrict__ outF, float* __restrict__ skip) {
    int idx = blockIdx.x * 256 + threadIdx.x;
    if (idx >= NB * T_LEN * 64) return;
    int c = idx & 63;
    int t = (idx >> 6) & (T_LEN - 1);
    int b = idx >> 20;
    int xs = (t == 0) ? 0 : x[b * T_LEN + t - 1];
    outF[idx] = firstWT[xs * 64 + c];
    skip[idx] = 0.f;
}

// ---------------------------------------------------------------------------
// ConvIn: valid conv, kernel 5, (B,80,68) -> (B,80,64)
// ---------------------------------------------------------------------------
__global__ void k_convin(const float* __restrict__ feat, const float* __restrict__ W,
                         float* __restrict__ f0) {
    int idx = blockIdx.x * 256 + threadIdx.x;
    if (idx >= NB * FCH * 64) return;
    int t = idx & 63;
    int o = (idx >> 6) % FCH;
    int b = idx / (64 * FCH);
    const float* fb = feat + b * FCH * TFRAMES;
    const float* wo = W + o * FCH * 5;
    float acc = 0.f;
    for (int i = 0; i < FCH; ++i) {
        const float* fi = fb + i * TFRAMES + t;
        const float* wi = wo + i * 5;
#pragma unroll
        for (int k = 0; k < 5; ++k) acc += fi[k] * wi[k];
    }
    f0[idx] = acc;
}

// ---------------------------------------------------------------------------
// Upsample stage (x4 repeat + 9-tap smooth), fp32 c-major
// ---------------------------------------------------------------------------
__global__ void k_up(const float* __restrict__ in, float* __restrict__ out,
                     const float* __restrict__ kern, int Tin) {
    int Tout = Tin * 4;
    int idx = blockIdx.x * 256 + threadIdx.x;
    if (idx >= NB * FCH * Tout) return;
    int t = idx % Tout;
    int bc = idx / Tout;
    const float* ib = in + bc * Tin;
    float acc = 0.f;
#pragma unroll
    for (int k = 0; k < 9; ++k) {
        int u = t + k - 4;
        if (u >= 0 && u < Tout) acc += kern[k] * ib[u >> 2];
    }
    out[idx] = acc;
}

// ---------------------------------------------------------------------------
// Last upsample -> bf16 TIME-MAJOR [b][t][96], LDS-staged source frames
// ---------------------------------------------------------------------------
__global__ __launch_bounds__(256)
void k_up_last(const float* __restrict__ in, unsigned short* __restrict__ outH,
               const float* __restrict__ kern) {
    __shared__ float sF[18 * 80];
    const int tid = threadIdx.x;
    const int b  = blockIdx.x >> 8;
    const int t0 = (blockIdx.x & 255) * 64;
    const int fr0 = (t0 >> 2) - 1;

    for (int idx = tid; idx < 18 * 80; idx += 256) {
        int c = idx / 18, fr = idx - c * 18;
        int gfr = fr0 + fr;
        float v = 0.f;
        if (gfr >= 0 && gfr < 4096) v = in[((size_t)b * 80 + c) * 4096 + gfr];
        sF[fr * 80 + c] = v;
    }
    float kr[9];
#pragma unroll
    for (int k = 0; k < 9; ++k) kr[k] = kern[k];
    __syncthreads();

    for (int idx = tid; idx < 64 * 96; idx += 256) {
        int c = idx % 96;
        int t = idx / 96;
        float acc = 0.f;
        if (c < 80) {
            int ubase = t0 + t - 4;
#pragma unroll
            for (int k = 0; k < 9; ++k) {
                int fr = ((ubase + k) >> 2) - fr0;
                acc += kr[k] * sF[fr * 80 + c];
            }
        }
        outH[((size_t)b * T_LEN + t0 + t) * 96 + c] = f2bf(acc);
    }
}

// ---------------------------------------------------------------------------
// FAST-PATH layer: GEMM1 + gate, z -> global z-store (skip deferred),
// GEMM2 res-only, res_in prefetched to registers (no epilogue re-read).
// ---------------------------------------------------------------------------
__global__ __launch_bounds__(256, 4)
void k_layer2(const float* __restrict__ prevF, float* __restrict__ nextF,
              unsigned short* __restrict__ zl, const unsigned short* __restrict__ ffb,
              const unsigned short* __restrict__ ATb, const unsigned short* __restrict__ SRTb,
              const float* __restrict__ convB, const float* __restrict__ resB, int d)
{
    __shared__ __align__(16) unsigned short s_X[96 * 72];   // [u][c] bf16
    __shared__ __align__(16) unsigned short s_Z[32 * 72];   // [t][c] bf16

    const int tid = threadIdx.x;
    const int b   = blockIdx.x >> 9;
    const int t0  = (blockIdx.x & 511) * TILE;
    const int W   = TILE + 2 * d;

    const int lane = tid & 63;
    const int wv   = tid >> 6;
    const int col  = lane & 15;
    const int quad = lane >> 4;
    const int ch   = 16 * wv + 4 * quad;

    // prefetch epilogue res_in (own cache lines, latency hidden behind GEMM1)
    f32x4 resIn[2];
#pragma unroll
    for (int nt = 0; nt < 2; ++nt)
        resIn[nt] = *(const f32x4*)(prevF +
                     (((size_t)b * T_LEN) + t0 + nt * 16 + col) * 64 + ch);

    // stage residual tile+halo fp32->bf16
    {
        const float* xb = prevF + ((size_t)b * T_LEN) * 64;
        for (int idx = tid; idx < W * 8; idx += 256) {
            int u = idx >> 3, seg = idx & 7;
            int g = t0 - 2 * d + u;
            bf16x8 v = {0, 0, 0, 0, 0, 0, 0, 0};
            if (g >= 0) {
                const float* p = xb + (size_t)g * 64 + seg * 8;
                f32x4 a0 = *(const f32x4*)p;
                f32x4 a1 = *(const f32x4*)(p + 4);
                v[0] = (short)f2bf(a0[0]); v[1] = (short)f2bf(a0[1]);
                v[2] = (short)f2bf(a0[2]); v[3] = (short)f2bf(a0[3]);
                v[4] = (short)f2bf(a1[0]); v[5] = (short)f2bf(a1[1]);
                v[6] = (short)f2bf(a1[2]); v[7] = (short)f2bf(a1[3]);
            }
            *(bf16x8*)(&s_X[u * 72 + seg * 8]) = v;
        }
    }

    // preload GEMM1 A-fragments
    bf16x8 frA[2][9];
#pragma unroll
    for (int p = 0; p < 2; ++p)
#pragma unroll
        for (int ks = 0; ks < 9; ++ks)
            frA[p][ks] = *(const bf16x8*)(ATb + (size_t)(16 * wv + 64 * p + col) * 288
                                          + ks * 32 + quad * 8);

    f32x4 acc[2][2];
#pragma unroll
    for (int p = 0; p < 2; ++p)
#pragma unroll
        for (int nt = 0; nt < 2; ++nt) acc[p][nt] = (f32x4){0.f, 0.f, 0.f, 0.f};

    const unsigned short* fp = ffb + ((size_t)b * T_LEN + t0) * 96;

    __syncthreads();

    // GEMM1: h(128 x 32t) = AT^T * [X-taps ; F], K = 288
#pragma unroll
    for (int ks = 0; ks < 9; ++ks) {
#pragma unroll
        for (int nt = 0; nt < 2; ++nt) {
            bf16x8 fB;
            if (ks < 6) {
                int k = ks * 32 + quad * 8;
                int u = nt * 16 + col + (k >> 6) * d;
                fB = *(const bf16x8*)(&s_X[u * 72 + (k & 63)]);
            } else {
                fB = *(const bf16x8*)(fp + (nt * 16 + col) * 96 + (ks - 6) * 32 + quad * 8);
            }
            acc[0][nt] = __builtin_amdgcn_mfma_f32_16x16x32_bf16(frA[0][ks], fB, acc[0][nt], 0, 0, 0);
            acc[1][nt] = __builtin_amdgcn_mfma_f32_16x16x32_bf16(frA[1][ks], fB, acc[1][nt], 0, 0, 0);
        }
    }

    // bias + gated activation -> s_Z bf16
    f32x4 cbA = *(const f32x4*)(convB + ch);
    f32x4 cbG = *(const f32x4*)(convB + 64 + ch);
#pragma unroll
    for (int nt = 0; nt < 2; ++nt) {
        unsigned int pk[2];
#pragma unroll
        for (int r2 = 0; r2 < 2; ++r2) {
            float zz[2];
#pragma unroll
            for (int e = 0; e < 2; ++e) {
                float a = acc[0][nt][2 * r2 + e] + cbA[2 * r2 + e];
                float g = acc[1][nt][2 * r2 + e] + cbG[2 * r2 + e];
                float th = 1.f - 2.f * __builtin_amdgcn_rcpf(__expf(2.f * a) + 1.f);
                float sg = __builtin_amdgcn_rcpf(1.f + __expf(-g));
                zz[e] = th * sg;
            }
            pk[r2] = (unsigned int)f2bf(zz[0]) | ((unsigned int)f2bf(zz[1]) << 16);
        }
        unsigned int* zp = (unsigned int*)(&s_Z[(nt * 16 + col) * 72 + ch]);
        zp[0] = pk[0];
        zp[1] = pk[1];
    }

    // preload GEMM2 A-fragments (res rows only: SRT rows 64..127)
    bf16x8 w10 = *(const bf16x8*)(SRTb + (size_t)(64 + 16 * wv + col) * 64 + quad * 8);
    bf16x8 w11 = *(const bf16x8*)(SRTb + (size_t)(64 + 16 * wv + col) * 64 + 32 + quad * 8);

    __syncthreads();

    // z copy-out (coalesced, fire-and-forget; hidden behind GEMM2)
    {
        int row = tid >> 3, seg = tid & 7;
        bf16x8 zv = *(const bf16x8*)(&s_Z[row * 72 + seg * 8]);
        *(bf16x8*)(zl + (((size_t)b * T_LEN) + t0 + row) * 64 + seg * 8) = zv;
    }

    // GEMM2: res(64 x 32t) = resW^T * Z, K = 64
    f32x4 acr[2];
    acr[0] = acr[1] = (f32x4){0.f, 0.f, 0.f, 0.f};
#pragma unroll
    for (int nt = 0; nt < 2; ++nt) {
        bf16x8 fz0 = *(const bf16x8*)(&s_Z[(nt * 16 + col) * 72 + quad * 8]);
        bf16x8 fz1 = *(const bf16x8*)(&s_Z[(nt * 16 + col) * 72 + 32 + quad * 8]);
        acr[nt] = __builtin_amdgcn_mfma_f32_16x16x32_bf16(w10, fz0, acr[nt], 0, 0, 0);
        acr[nt] = __builtin_amdgcn_mfma_f32_16x16x32_bf16(w11, fz1, acr[nt], 0, 0, 0);
    }

    // epilogue: residual fp32 add from prefetched regs
    f32x4 rb4 = *(const f32x4*)(resB + ch);
#pragma unroll
    for (int nt = 0; nt < 2; ++nt) {
        f32x4 r = resIn[nt];
#pragma unroll
        for (int e = 0; e < 4; ++e) r[e] += acr[nt][e] + rb4[e];
        *(f32x4*)(nextF + (((size_t)b * T_LEN) + t0 + nt * 16 + col) * 64 + ch) = r;
    }
}

// ---------------------------------------------------------------------------
// FAST-PATH tail: skip = sum_l skipW_l @ z_l (K=1536, fp32 acc) + sbSum
//                 -> relu -> last1 -> relu -> last2 -> out. One kernel.
// Waves split K (wave w: layers 6w..6w+5); LDS fp32 reduction.
// ---------------------------------------------------------------------------
__global__ __launch_bounds__(256)
void k_tail(const unsigned short* __restrict__ zst, const unsigned short* __restrict__ ASKb,
            const float* __restrict__ sbSum,
            const unsigned short* __restrict__ W1b, const float* __restrict__ b1,
            const unsigned short* __restrict__ W2b, const float* __restrict__ b2,
            float* __restrict__ out)
{
    __shared__ __align__(16) float s_red[64 * 68];           // [t][o] fp32
    __shared__ __align__(16) unsigned short s_S[64 * 72];    // relu(skip) bf16
    __shared__ __align__(16) unsigned short s_H[64 * 72];    // h2 bf16

    const int tid = threadIdx.x;
    const int b   = blockIdx.x >> 8;
    const int t0  = (blockIdx.x & 255) * 64;
    const int lane = tid & 63, wv = tid >> 6, col = lane & 15, quad = lane >> 4;

    // skip GEMM: this wave covers K-range [wv*384, wv*384+384)
    f32x4 acc[4][4];
#pragma unroll
    for (int rt = 0; rt < 4; ++rt)
#pragma unroll
        for (int nt = 0; nt < 4; ++nt) acc[rt][nt] = (f32x4){0.f, 0.f, 0.f, 0.f};

    for (int ks = 0; ks < 12; ++ks) {
        const int kk = wv * 384 + ks * 32;
        bf16x8 fa[4];
#pragma unroll
        for (int rt = 0; rt < 4; ++rt)
            fa[rt] = *(const bf16x8*)(ASKb + (size_t)(16 * rt + col) * 1536 + kk + quad * 8);
        const int k = kk + quad * 8;
        const int l = k >> 6, c = k & 63;
        const unsigned short* zb = zst + (((size_t)l * NB + b) * T_LEN + t0) * 64 + c;
#pragma unroll
        for (int nt = 0; nt < 4; ++nt) {
            bf16x8 fb = *(const bf16x8*)(zb + (size_t)(nt * 16 + col) * 64);
#pragma unroll
            for (int rt = 0; rt < 4; ++rt)
                acc[rt][nt] = __builtin_amdgcn_mfma_f32_16x16x32_bf16(fa[rt], fb, acc[rt][nt], 0, 0, 0);
        }
    }

    // cross-wave fp32 reduction in LDS
    for (int w = 0; w < 4; ++w) {
        if (wv == w) {
#pragma unroll
            for (int rt = 0; rt < 4; ++rt)
#pragma unroll
                for (int nt = 0; nt < 4; ++nt) {
                    float* p = &s_red[(nt * 16 + col) * 68 + rt * 16 + 4 * quad];
                    if (w == 0) *(f32x4*)p = acc[rt][nt];
                    else {
                        f32x4 v = *(f32x4*)p;
#pragma unroll
                        for (int e = 0; e < 4; ++e) v[e] += acc[rt][nt][e];
                        *(f32x4*)p = v;
                    }
                }
        }
        __syncthreads();
    }

    // + sbSum, relu -> bf16 s_S
    for (int i = tid; i < 64 * 64; i += 256) {
        int t = i >> 6, c = i & 63;
        float v = s_red[t * 68 + c] + sbSum[c];
        s_S[t * 72 + c] = f2bf(v > 0.f ? v : 0.f);
    }
    __syncthreads();

    // last1: h2 = relu(W1 @ s_S + b1)
    f32x4 aL[4];
#pragma unroll
    for (int nt = 0; nt < 4; ++nt) aL[nt] = (f32x4){0.f, 0.f, 0.f, 0.f};
#pragma unroll
    for (int ks = 0; ks < 2; ++ks) {
        bf16x8 fw = *(const bf16x8*)(W1b + (size_t)(16 * wv + col) * 64 + ks * 32 + quad * 8);
#pragma unroll
        for (int nt = 0; nt < 4; ++nt) {
            bf16x8 fz = *(const bf16x8*)(&s_S[(nt * 16 + col) * 72 + ks * 32 + quad * 8]);
            aL[nt] = __builtin_amdgcn_mfma_f32_16x16x32_bf16(fw, fz, aL[nt], 0, 0, 0);
        }
    }
    f32x4 bb1 = *(const f32x4*)(b1 + 16 * wv + 4 * quad);
#pragma unroll
    for (int nt = 0; nt < 4; ++nt) {
        float h0 = fmaxf(aL[nt][0] + bb1[0], 0.f), h1 = fmaxf(aL[nt][1] + bb1[1], 0.f);
        float h2 = fmaxf(aL[nt][2] + bb1[2], 0.f), h3 = fmaxf(aL[nt][3] + bb1[3], 0.f);
        unsigned int* hp = (unsigned int*)(&s_H[(nt * 16 + col) * 72 + 16 * wv + 4 * quad]);
        hp[0] = (unsigned int)f2bf(h0) | ((unsigned int)f2bf(h1) << 16);
        hp[1] = (unsigned int)f2bf(h2) | ((unsigned int)f2bf(h3) << 16);
    }
    __syncthreads();

    // last2: out = W2 @ h2 + b2  (fp32 c-major)
    f32x4 aO[4][4];
#pragma unroll
    for (int p = 0; p < 4; ++p)
#pragma unroll
        for (int nt = 0; nt < 4; ++nt) aO[p][nt] = (f32x4){0.f, 0.f, 0.f, 0.f};
#pragma unroll
    for (int ks = 0; ks < 2; ++ks) {
#pragma unroll
        for (int nt = 0; nt < 4; ++nt) {
            bf16x8 fz = *(const bf16x8*)(&s_H[(nt * 16 + col) * 72 + ks * 32 + quad * 8]);
#pragma unroll
            for (int p = 0; p < 4; ++p) {
                bf16x8 fw = *(const bf16x8*)(W2b + (size_t)(16 * (wv + 4 * p) + col) * 64
                                             + ks * 32 + quad * 8);
                aO[p][nt] = __builtin_amdgcn_mfma_f32_16x16x32_bf16(fw, fz, aO[p][nt], 0, 0, 0);
            }
        }
    }
#pragma unroll
    for (int p = 0; p < 4; ++p) {
        int o0 = 16 * (wv + 4 * p) + 4 * quad;
        f32x4 bb2 = *(const f32x4*)(b2 + o0);
#pragma unroll
        for (int nt = 0; nt < 4; ++nt) {
            int t = t0 + nt * 16 + col;
#pragma unroll
            for (int e = 0; e < 4; ++e)
                out[((size_t)b * 256 + o0 + e) * T_LEN + t] = aO[p][nt][e] + bb2[e];
        }
    }
}

// ---------------------------------------------------------------------------
// FALLBACK path (round-3 kernels), used only if ws_size too small
// ---------------------------------------------------------------------------
__global__ __launch_bounds__(256, 4)
void k_layer_fb(const float* __restrict__ prevF, float* __restrict__ nextF,
                float* __restrict__ skip, const unsigned short* __restrict__ ffb,
                const unsigned short* __restrict__ ATb, const unsigned short* __restrict__ SRTb,
                const float* __restrict__ convB, const float* __restrict__ skipB,
                const float* __restrict__ resB, int d)
{
    __shared__ __align__(16) unsigned short s_X[96 * 72];
    __shared__ __align__(16) unsigned short s_Z[32 * 72];
    const int tid = threadIdx.x;
    const int b   = blockIdx.x >> 9;
    const int t0  = (blockIdx.x & 511) * TILE;
    const int W   = TILE + 2 * d;
    {
        const float* xb = prevF + ((size_t)b * T_LEN) * 64;
        for (int idx = tid; idx < W * 8; idx += 256) {
            int u = idx >> 3, seg = idx & 7;
            int g = t0 - 2 * d + u;
            bf16x8 v = {0, 0, 0, 0, 0, 0, 0, 0};
            if (g >= 0) {
                const float* p = xb + (size_t)g * 64 + seg * 8;
                f32x4 x0 = *(const f32x4*)p;
                f32x4 x1 = *(const f32x4*)(p + 4);
                v[0] = (short)f2bf(x0[0]); v[1] = (short)f2bf(x0[1]);
                v[2] = (short)f2bf(x0[2]); v[3] = (short)f2bf(x0[3]);
                v[4] = (short)f2bf(x1[0]); v[5] = (short)f2bf(x1[1]);
                v[6] = (short)f2bf(x1[2]); v[7] = (short)f2bf(x1[3]);
            }
            *(bf16x8*)(&s_X[u * 72 + seg * 8]) = v;
        }
    }
    const int lane = tid & 63, wv = tid >> 6, col = lane & 15, quad = lane >> 4;
    bf16x8 frA[2][9];
#pragma unroll
    for (int p = 0; p < 2; ++p)
#pragma unroll
        for (int ks = 0; ks < 9; ++ks)
            frA[p][ks] = *(const bf16x8*)(ATb + (size_t)(16 * wv + 64 * p + col) * 288
                                          + ks * 32 + quad * 8);
    f32x4 acc[2][2];
#pragma unroll
    for (int p = 0; p < 2; ++p)
#pragma unroll
        for (int nt = 0; nt < 2; ++nt) acc[p][nt] = (f32x4){0.f, 0.f, 0.f, 0.f};
    const unsigned short* fp = ffb + ((size_t)b * T_LEN + t0) * 96;
    __syncthreads();
#pragma unroll
    for (int ks = 0; ks < 9; ++ks) {
#pragma unroll
        for (int nt = 0; nt < 2; ++nt) {
            bf16x8 fB;
            if (ks < 6) {
                int k = ks * 32 + quad * 8;
                int u = nt * 16 + col + (k >> 6) * d;
                fB = *(const bf16x8*)(&s_X[u * 72 + (k & 63)]);
            } else {
                fB = *(const bf16x8*)(fp + (nt * 16 + col) * 96 + (ks - 6) * 32 + quad * 8);
            }
            acc[0][nt] = __builtin_amdgcn_mfma_f32_16x16x32_bf16(frA[0][ks], fB, acc[0][nt], 0, 0, 0);
            acc[1][nt] = __builtin_amdgcn_mfma_f32_16x16x32_bf16(frA[1][ks], fB, acc[1][nt], 0, 0, 0);
        }
    }
    f32x4 cbA = *(const f32x4*)(convB + 16 * wv + quad * 4);
    f32x4 cbG = *(const f32x4*)(convB + 64 + 16 * wv + quad * 4);
#pragma unroll
    for (int nt = 0; nt < 2; ++nt) {
        unsigned int pk[2];
#pragma unroll
        for (int r2 = 0; r2 < 2; ++r2) {
            float zz[2];
#pragma unroll
            for (int e = 0; e < 2; ++e) {
                float a = acc[0][nt][2 * r2 + e] + cbA[2 * r2 + e];
                float g = acc[1][nt][2 * r2 + e] + cbG[2 * r2 + e];
                float th = 1.f - 2.f * __builtin_amdgcn_rcpf(__expf(2.f * a) + 1.f);
                float sg = __builtin_amdgcn_rcpf(1.f + __expf(-g));
                zz[e] = th * sg;
            }
            pk[r2] = (unsigned int)f2bf(zz[0]) | ((unsigned int)f2bf(zz[1]) << 16);
        }
        unsigned int* zp = (unsigned int*)(&s_Z[(nt * 16 + col) * 72 + 16 * wv + quad * 4]);
        zp[0] = pk[0];
        zp[1] = pk[1];
    }
    bf16x8 frA2[2][2];
#pragma unroll
    for (int p = 0; p < 2; ++p)
#pragma unroll
        for (int ks = 0; ks < 2; ++ks)
            frA2[p][ks] = *(const bf16x8*)(SRTb + (size_t)(16 * wv + 64 * p + col) * 64
                                           + ks * 32 + quad * 8);
    __syncthreads();
    f32x4 acc2[2][2];
#pragma unroll
    for (int p = 0; p < 2; ++p)
#pragma unroll
        for (int nt = 0; nt < 2; ++nt) acc2[p][nt] = (f32x4){0.f, 0.f, 0.f, 0.f};
#pragma unroll
    for (int ks = 0; ks < 2; ++ks)
#pragma unroll
        for (int nt = 0; nt < 2; ++nt) {
            bf16x8 fz = *(const bf16x8*)(&s_Z[(nt * 16 + col) * 72 + ks * 32 + quad * 8]);
            acc2[0][nt] = __builtin_amdgcn_mfma_f32_16x16x32_bf16(frA2[0][ks], fz, acc2[0][nt], 0, 0, 0);
            acc2[1][nt] = __builtin_amdgcn_mfma_f32_16x16x32_bf16(frA2[1][ks], fz, acc2[1][nt], 0, 0, 0);
        }
    f32x4 sb4 = *(const f32x4*)(skipB + 16 * wv + quad * 4);
    f32x4 rb4 = *(const f32x4*)(resB + 16 * wv + quad * 4);
#pragma unroll
    for (int nt = 0; nt < 2; ++nt) {
        size_t base = (((size_t)b * T_LEN) + t0 + nt * 16 + col) * 64 + 16 * wv + quad * 4;
        f32x4 s = *(f32x4*)(skip + base);
        f32x4 r = *(const f32x4*)(prevF + base);
#pragma unroll
        for (int e = 0; e < 4; ++e) {
            s[e] += acc2[0][nt][e] + sb4[e];
            r[e] += acc2[1][nt][e] + rb4[e];
        }
        *(f32x4*)(skip + base) = s;
        *(f32x4*)(nextF + base) = r;
    }
}

__global__ __launch_bounds__(256)
void k_last1(const float* __restrict__ skip, const unsigned short* __restrict__ W1b,
             const float* __restrict__ b1, unsigned short* __restrict__ h2b) {
    __shared__ __align__(16) unsigned short s_S[64 * 72];
    const int tid = threadIdx.x;
    const int b = blockIdx.x >> 8;
    const int t0 = (blockIdx.x & 255) * 64;
    const float* sp = skip + (((size_t)b * T_LEN) + t0) * 64;
    for (int idx = tid; idx < 64 * 32; idx += 256) {
        int t = idx >> 5, c2 = idx & 31;
        float v0 = fmaxf(sp[t * 64 + 2 * c2], 0.f);
        float v1 = fmaxf(sp[t * 64 + 2 * c2 + 1], 0.f);
        *(unsigned int*)(&s_S[t * 72 + 2 * c2]) =
            (unsigned int)f2bf(v0) | ((unsigned int)f2bf(v1) << 16);
    }
    const int lane = tid & 63, wv = tid >> 6, col = lane & 15, quad = lane >> 4;
    bf16x8 fa[2];
#pragma unroll
    for (int ks = 0; ks < 2; ++ks)
        fa[ks] = *(const bf16x8*)(W1b + (16 * wv + col) * 64 + ks * 32 + quad * 8);
    f32x4 acc[4];
#pragma unroll
    for (int nt = 0; nt < 4; ++nt) acc[nt] = (f32x4){0.f, 0.f, 0.f, 0.f};
    __syncthreads();
#pragma unroll
    for (int ks = 0; ks < 2; ++ks)
#pragma unroll
        for (int nt = 0; nt < 4; ++nt) {
            bf16x8 fz = *(const bf16x8*)(&s_S[(nt * 16 + col) * 72 + ks * 32 + quad * 8]);
            acc[nt] = __builtin_amdgcn_mfma_f32_16x16x32_bf16(fa[ks], fz, acc[nt], 0, 0, 0);
        }
    f32x4 bb = *(const f32x4*)(b1 + 16 * wv + quad * 4);
#pragma unroll
    for (int nt = 0; nt < 4; ++nt) {
        float h0 = fmaxf(acc[nt][0] + bb[0], 0.f), h1 = fmaxf(acc[nt][1] + bb[1], 0.f);
        float h2 = fmaxf(acc[nt][2] + bb[2], 0.f), h3 = fmaxf(acc[nt][3] + bb[3], 0.f);
        unsigned short* hp = h2b + (((size_t)b * T_LEN) + t0 + nt * 16 + col) * 64
                             + 16 * wv + quad * 4;
        ((unsigned int*)hp)[0] = (unsigned int)f2bf(h0) | ((unsigned int)f2bf(h1) << 16);
        ((unsigned int*)hp)[1] = (unsigned int)f2bf(h2) | ((unsigned int)f2bf(h3) << 16);
    }
}

__global__ __launch_bounds__(256)
void k_last2(const unsigned short* __restrict__ h2b, const unsigned short* __restrict__ W2b,
             const float* __restrict__ b2, float* __restrict__ out) {
    __shared__ __align__(16) unsigned short s_H[64 * 72];
    const int tid = threadIdx.x;
    const int b = blockIdx.x >> 8;
    const int t0 = (blockIdx.x & 255) * 64;
    const unsigned short* hp = h2b + (((size_t)b * T_LEN) + t0) * 64;
    for (int idx = tid; idx < 64 * 8; idx += 256) {
        int t = idx >> 3, seg = idx & 7;
        *(bf16x8*)(&s_H[t * 72 + seg * 8]) = *(const bf16x8*)(hp + t * 64 + seg * 8);
    }
    const int lane = tid & 63, wv = tid >> 6, col = lane & 15, quad = lane >> 4;
    bf16x8 fa[4][2];
#pragma unroll
    for (int p = 0; p < 4; ++p)
#pragma unroll
        for (int ks = 0; ks < 2; ++ks)
            fa[p][ks] = *(const bf16x8*)(W2b + (size_t)(16 * (wv + 4 * p) + col) * 64
                                         + ks * 32 + quad * 8);
    f32x4 acc[4][4];
#pragma unroll
    for (int p = 0; p < 4; ++p)
#pragma unroll
        for (int nt = 0; nt < 4; ++nt) acc[p][nt] = (f32x4){0.f, 0.f, 0.f, 0.f};
    __syncthreads();
#pragma unroll
    for (int ks = 0; ks < 2; ++ks)
#pragma unroll
        for (int nt = 0; nt < 4; ++nt) {
            bf16x8 fz = *(const bf16x8*)(&s_H[(nt * 16 + col) * 72 + ks * 32 + quad * 8]);
#pragma unroll
            for (int p = 0; p < 4; ++p)
                acc[p][nt] = __builtin_amdgcn_mfma_f32_16x16x32_bf16(fa[p][ks], fz, acc[p][nt], 0, 0, 0);
        }
#pragma unroll
    for (int p = 0; p < 4; ++p) {
        f32x4 bb = *(const f32x4*)(b2 + 16 * (wv + 4 * p) + quad * 4);
#pragma unroll
        for (int nt = 0; nt < 4; ++nt) {
            int t = t0 + nt * 16 + col;
#pragma unroll
            for (int e = 0; e < 4; ++e) {
                int o = 16 * (wv + 4 * p) + quad * 4 + e;
                out[((size_t)b * 256 + o) * T_LEN + t] = acc[p][nt][e] + bb[e];
            }
        }
    }
}

// ---------------------------------------------------------------------------
extern "C" void kernel_launch(void* const* d_in, const int* in_sizes, int n_in,
                              void* d_out, int out_size, void* d_ws, size_t ws_size,
                              hipStream_t stream) {
    const int*   x       = (const int*)  d_in[0];
    const float* feature = (const float*)d_in[1];
    const float* firstW  = (const float*)d_in[2];
    const float* firstb  = (const float*)d_in[3];
    const float* convW   = (const float*)d_in[4];
    const float* convB   = (const float*)d_in[5];
    const float* condW   = (const float*)d_in[6];
    const float* skipW   = (const float*)d_in[7];
    const float* skipB   = (const float*)d_in[8];
    const float* resW    = (const float*)d_in[9];
    const float* resB    = (const float*)d_in[10];
    const float* last1W  = (const float*)d_in[11];
    const float* last1b  = (const float*)d_in[12];
    const float* last2W  = (const float*)d_in[13];
    const float* last2b  = (const float*)d_in[14];
    const float* convinW = (const float*)d_in[15];
    const float* upK     = (const float*)d_in[16];

    float* ws = (float*)d_ws;
    float* f0      = ws;                       // 10240
    float* f1      = f0 + 10240;               // 40960
    float* f2      = f1 + 40960;               // 163840
    float* f3      = f2 + 163840;              // 655360
    float* firstWT = f3 + 655360;              // 16384
    float* resA    = firstWT + 16384;          // 2097152
    float* resB_   = resA + 2097152;           // 2097152
    float* sbSum   = resB_ + 2097152;          // 64
    unsigned short* ub   = (unsigned short*)(sbSum + 64);
    unsigned short* ffb  = ub;                 // 3145728
    unsigned short* ATb  = ffb + 3145728;      // 884736
    unsigned short* SRTb = ATb + 884736;       // 196608
    unsigned short* W1b  = SRTb + 196608;      // 4096
    unsigned short* W2b  = W1b + 4096;         // 16384
    unsigned short* ASKb = W2b + 16384;        // 98304
    unsigned short* zst  = ASKb + 98304;       // 50331648 (fast path only)
    // fallback carves from zst region:
    float*          skipF = (float*)zst;               // 2097152 f
    unsigned short* h2b   = zst + 4194304;             // 2097152 ush

    const size_t FAST_NEED = (size_t)(5081152) * 4 + (size_t)(4345856 + 50331648) * 2;

    int n;
    n = NLAYERS * 128 * 288 + NLAYERS * 128 * 64 + 4096 + 16384 + 16384 + 64 * 1536 + 64;
    k_pack<<<(n + 255) / 256, 256, 0, stream>>>(convW, condW, skipW, resW, last1W, last2W,
                                                firstW, firstb, skipB,
                                                ATb, SRTb, W1b, W2b, firstWT, ASKb, sbSum);
    n = NB * FCH * 64;
    k_convin<<<(n + 255) / 256, 256, 0, stream>>>(feature, convinW, f0);
    k_up<<<(NB * FCH * 256 + 255) / 256, 256, 0, stream>>>(f0, f1, upK + 0, 64);
    k_up<<<(NB * FCH * 1024 + 255) / 256, 256, 0, stream>>>(f1, f2, upK + 9, 256);
    k_up<<<(NB * FCH * 4096 + 255) / 256, 256, 0, stream>>>(f2, f3, upK + 18, 1024);
    k_up_last<<<NB * 256, 256, 0, stream>>>(f3, ffb, upK + 27);

    if (ws_size >= FAST_NEED) {
        n = NB * T_LEN * 64;
        k_embed2<<<(n + 255) / 256, 256, 0, stream>>>(x, firstWT, resA);
        float* poF = resA;
        float* pnF = resB_;
        for (int l = 0; l < NLAYERS; ++l) {
            int d = 1 << (l % 6);
            k_layer2<<<NB * (T_LEN / TILE), 256, 0, stream>>>(
                poF, pnF, zst + (size_t)l * NB * T_LEN * 64, ffb,
                ATb + (size_t)l * 128 * 288, SRTb + (size_t)l * 128 * 64,
                convB + l * 128, resB + l * 64, d);
            float* tf = poF; poF = pnF; pnF = tf;
        }
        k_tail<<<NB * 256, 256, 0, stream>>>(zst, ASKb, sbSum, W1b, last1b, W2b, last2b,
                                             (float*)d_out);
    } else {
        n = NB * T_LEN * 64;
        k_embed_f<<<(n + 255) / 256, 256, 0, stream>>>(x, firstWT, resA, skipF);
        float* poF = resA;
        float* pnF = resB_;
        for (int l = 0; l < NLAYERS; ++l) {
            int d = 1 << (l % 6);
            k_layer_fb<<<NB * (T_LEN / TILE), 256, 0, stream>>>(
                poF, pnF, skipF, ffb,
                ATb + (size_t)l * 128 * 288, SRTb + (size_t)l * 128 * 64,
                convB + l * 128, skipB + l * 64, resB + l * 64, d);
            float* tf = poF; poF = pnF; pnF = tf;
        }
        k_last1<<<NB * 256, 256, 0, stream>>>(skipF, W1b, last1b, h2b);
        k_last2<<<NB * 256, 256, 0, stream>>>(h2b, W2b, last2b, (float*)d_out);
    }
}